// Round 3
// baseline (336.619 us; speedup 1.0000x reference)
//
#include <hip/hip_runtime.h>
#include <hip/hip_bf16.h>

// SKConv2d: reference collapses algebraically to a single 3x3 conv:
//   out = conv3x3(x, W_eff) + bias,  W_eff[k][o] = (sum_t S1s[t]@U1s[t] + U2s[t]^T@S2s[t])[k][o] / 12
// Implemented as implicit GEMM with bf16 hi/lo split (3 MFMA passes) for ~fp32 accuracy.
//
// dims
#define B_   16
#define CIN_ 256
#define COUT_ 256
#define HW_  56
#define SP_  3136            // 56*56
#define KCIN_ 2304
#define T_   6
#define R_   8
#define KR_  72

// ws layout (ushort units)
#define WC_ELEMS  (9*256*512)        // 1,179,648  : Wc[s][o][c8][hi32|lo32]
#define XC_ELEMS  (16*3136*512)      // 25,690,112 : Xc[b*3136+sp][c8][hi32|lo32]
#define ZERO_ELEMS 512
// total ws bytes needed = (WC_ELEMS + XC_ELEMS + ZERO_ELEMS)*2 = 53,740,544

typedef __attribute__((ext_vector_type(4))) float f32x4;
typedef __attribute__((ext_vector_type(8))) short short8;

__device__ __forceinline__ void gld16(const void* g, void* l) {
  __builtin_amdgcn_global_load_lds(
      (const __attribute__((address_space(1))) void*)g,
      (__attribute__((address_space(3))) void*)l, 16, 0, 0);
}

// ---------------------------------------------------------------------------
// Kernel 1: W_eff = (sum_t S1s[t]@U1s[t] + U2s[t]^T@S2s[t]) / 12, split hi/lo bf16.
// Store layout: Wc[((s*256 + o)*8 + c8)*64 + slot*8 + j], slot = (half?4:0)+(cwithin32/8)
// k = c*9 + s  (s = kh*3+kw), matching unfold (c,kh,kw) ordering.
// ---------------------------------------------------------------------------
__global__ __launch_bounds__(256) void build_w(
    const float* __restrict__ S1s, const float* __restrict__ S2s,
    const float* __restrict__ U1s, const float* __restrict__ U2s,
    unsigned short* __restrict__ Wc, float* __restrict__ zf)
{
  __shared__ float s1[48];
  __shared__ float u2[432];
  const int k = blockIdx.x;      // 0..2303
  const int o = threadIdx.x;     // 0..255
  if (o < 48) { int t = o >> 3, r = o & 7; s1[o] = S1s[t*18432 + k*8 + r]; }
  for (int i = o; i < 432; i += 256) u2[i] = U2s[(size_t)i*2304 + k];
  __syncthreads();
  float acc = 0.f;
  #pragma unroll 8
  for (int i = 0; i < 48; ++i)  acc += s1[i] * U1s[i*256 + o];
  #pragma unroll 8
  for (int i = 0; i < 432; ++i) acc += u2[i] * S2s[i*256 + o];
  acc *= (1.0f/12.0f);
  __hip_bfloat16 h = __float2bfloat16(acc);
  float hv = __bfloat162float(h);
  __hip_bfloat16 l = __float2bfloat16(acc - hv);
  const int c = k / 9, s = k % 9;
  const int base = ((s*256 + o)*8 + (c >> 5))*64 + (c & 31);
  Wc[base]      = *(const unsigned short*)&h;
  Wc[base + 32] = *(const unsigned short*)&l;
  if (k == 0) zf[o] = 0.f;     // 1KB zero page for padded-pixel loads
}

// ---------------------------------------------------------------------------
// Kernel 2: x [B][C][H][W] fp32 -> Xc [B*SP][8][hi32|lo32] bf16 (NHWC, hi/lo split)
// ---------------------------------------------------------------------------
__global__ __launch_bounds__(256) void split_x(
    const float* __restrict__ x, unsigned short* __restrict__ Xc)
{
  const int t  = threadIdx.x;
  const int sp = blockIdx.x*64 + (t >> 2);
  const int cg = blockIdx.y;           // 0..7 (c8)
  const int b  = blockIdx.z;
  const int c0 = cg*32 + (t & 3)*8;
  const float* src = x + ((size_t)(b*256 + c0))*3136 + sp;
  __align__(16) unsigned short h8[8];
  __align__(16) unsigned short l8[8];
  #pragma unroll
  for (int j = 0; j < 8; ++j) {
    float v = src[(size_t)j*3136];
    __hip_bfloat16 h = __float2bfloat16(v);
    float hv = __bfloat162float(h);
    __hip_bfloat16 l = __float2bfloat16(v - hv);
    h8[j] = *(const unsigned short*)&h;
    l8[j] = *(const unsigned short*)&l;
  }
  unsigned short* dst = Xc + ((size_t)(b*3136 + sp))*512 + cg*64 + (t & 3)*8;
  *(uint4*)dst        = *(const uint4*)h8;
  *(uint4*)(dst + 32) = *(const uint4*)l8;
}

// ---------------------------------------------------------------------------
// Kernel 3: implicit-GEMM conv.  C[o][n] = sum_k W[o][k] * X[k][n]
// BM=256 (all COUT), BN=64 spatial (divides 3136 -> no batch straddle), BK=32.
// 8 waves = 4(o) x 2(n); per-wave 64o x 32n = 4x2 frags of 16x16x32 bf16.
// LDS rows = 128B: [hi 32c | lo 32c] interleaved; slot' = slot ^ (row&7) XOR
// swizzle -> conflict-free ds_read_b128. Staged via global_load_lds(16B) with
// pre-swizzled per-lane global addresses (linear LDS dest).
// 3 MFMA passes: hi*hi + hi*lo + lo*hi  (Ootomo split, ~1e-5 abs error).
// ---------------------------------------------------------------------------
__global__ __launch_bounds__(512, 4) void skconv_gemm(
    const unsigned short* __restrict__ Wc, const unsigned short* __restrict__ Xc,
    const unsigned short* __restrict__ zerobuf, const float* __restrict__ bias,
    float* __restrict__ out)
{
  __shared__ __align__(16) unsigned short lds[20480];  // A: [0,16384) B: [16384,20480)
  const int t = threadIdx.x;
  const int lane = t & 63, wid = t >> 6;
  const int blk = blockIdx.x;
  const int b   = blk / 49;
  const int sp0 = (blk % 49) * 64;

  // ---- A staging: 2048 chunks of 16B, 4 per thread ----
  int aoff[4];
  #pragma unroll
  for (int i = 0; i < 4; ++i) {
    int c  = i*512 + t;
    int o  = c >> 3, ph = c & 7;
    aoff[i] = o*512 + ((ph ^ (o & 7)) * 8);   // ushort offset within (s,c8) plane
  }
  // ---- B staging: 512 chunks, 1 per thread ----
  const int bn   = t >> 3;                 // 0..63 spatial row
  const int bls  = (t & 7) ^ (bn & 7);     // logical slot for this phys slot
  const int bco  = bls * 8;
  const int p    = sp0 + bn;
  const int prow = p / 56, pcol = p % 56;

  // ---- fragment read offsets (ushort units) ----
  const int hs  = ((lane >> 4) ^ (lane & 7)) * 8;   // swizzled hi-slot offset
  const int r15 = lane & 15;
  const int wr  = wid >> 1, wcn = wid & 1;
  int ard[4], brd[2];
  #pragma unroll
  for (int mi = 0; mi < 4; ++mi) ard[mi] = (wr*64 + mi*16 + r15)*64 + hs;
  #pragma unroll
  for (int ni = 0; ni < 2; ++ni) brd[ni] = 16384 + (wcn*32 + ni*16 + r15)*64 + hs;

  char* ldsc = (char*)lds;
  char* aDst0 = ldsc + 0*8192  + wid*1024;
  char* aDst1 = ldsc + 1*8192  + wid*1024;
  char* aDst2 = ldsc + 2*8192  + wid*1024;
  char* aDst3 = ldsc + 3*8192  + wid*1024;
  char* bDst  = ldsc + 32768   + wid*1024;

  const f32x4 z4 = {0.f, 0.f, 0.f, 0.f};
  f32x4 acc[4][2];
  #pragma unroll
  for (int mi = 0; mi < 4; ++mi) { acc[mi][0] = z4; acc[mi][1] = z4; }

  #pragma unroll 1
  for (int s = 0; s < 9; ++s) {
    const int kh = s/3 - 1, kw = s%3 - 1;
    const int h2 = prow + kh, w2 = pcol + kw;
    const bool valid = ((unsigned)h2 < 56u) && ((unsigned)w2 < 56u);
    const long long pix = ((long long)(b*3136) + h2*56 + w2)*512 + bco;
    const unsigned short* bs = valid ? (Xc + pix) : zerobuf;
    const unsigned short* as = Wc + s*131072;
    #pragma unroll 1
    for (int c8 = 0; c8 < 8; ++c8) {
      const unsigned short* asc = as + c8*64;
      gld16(asc + aoff[0], aDst0);
      gld16(asc + aoff[1], aDst1);
      gld16(asc + aoff[2], aDst2);
      gld16(asc + aoff[3], aDst3);
      gld16(bs + c8*64,    bDst);
      __syncthreads();                       // vmcnt(0): staging complete
      short8 bh0 = *(const short8*)&lds[brd[0]];
      short8 bh1 = *(const short8*)&lds[brd[1]];
      short8 bl0 = *(const short8*)&lds[brd[0] ^ 32];
      short8 bl1 = *(const short8*)&lds[brd[1] ^ 32];
      #pragma unroll
      for (int mi = 0; mi < 4; ++mi) {
        short8 ah = *(const short8*)&lds[ard[mi]];
        short8 al = *(const short8*)&lds[ard[mi] ^ 32];
        acc[mi][0] = __builtin_amdgcn_mfma_f32_16x16x32_bf16(ah, bh0, acc[mi][0], 0,0,0);
        acc[mi][1] = __builtin_amdgcn_mfma_f32_16x16x32_bf16(ah, bh1, acc[mi][1], 0,0,0);
        acc[mi][0] = __builtin_amdgcn_mfma_f32_16x16x32_bf16(ah, bl0, acc[mi][0], 0,0,0);
        acc[mi][1] = __builtin_amdgcn_mfma_f32_16x16x32_bf16(ah, bl1, acc[mi][1], 0,0,0);
        acc[mi][0] = __builtin_amdgcn_mfma_f32_16x16x32_bf16(al, bh0, acc[mi][0], 0,0,0);
        acc[mi][1] = __builtin_amdgcn_mfma_f32_16x16x32_bf16(al, bh1, acc[mi][1], 0,0,0);
      }
      __syncthreads();                       // all reads done before next stage
    }
  }

  // ---- epilogue: C col = lane&15 -> spatial n (contiguous stores), row -> o ----
  const int nbase = sp0 + wcn*32 + r15;
  #pragma unroll
  for (int mi = 0; mi < 4; ++mi) {
    const int o0 = wr*64 + mi*16 + ((lane >> 4) << 2);
    float bv[4];
    #pragma unroll
    for (int r = 0; r < 4; ++r) bv[r] = bias[o0 + r];
    #pragma unroll
    for (int ni = 0; ni < 2; ++ni) {
      #pragma unroll
      for (int r = 0; r < 4; ++r) {
        out[((size_t)(b*256 + o0 + r))*3136 + nbase + ni*16] = acc[mi][ni][r] + bv[r];
      }
    }
  }
}

extern "C" void kernel_launch(void* const* d_in, const int* in_sizes, int n_in,
                              void* d_out, int out_size, void* d_ws, size_t ws_size,
                              hipStream_t stream) {
  const float* x    = (const float*)d_in[0];
  const float* S1s  = (const float*)d_in[1];
  const float* S2s  = (const float*)d_in[2];
  const float* U1s  = (const float*)d_in[3];
  const float* U2s  = (const float*)d_in[4];
  const float* bias = (const float*)d_in[5];
  float* out = (float*)d_out;

  unsigned short* Wc = (unsigned short*)d_ws;
  unsigned short* Xc = Wc + WC_ELEMS;
  unsigned short* zb = Xc + XC_ELEMS;          // 512 ushorts of zeros
  // required ws: ~51.3 MiB (ws re-poisoned each call; all regions rewritten below)

  build_w<<<dim3(2304), dim3(256), 0, stream>>>(S1s, S2s, U1s, U2s, Wc, (float*)zb);
  split_x<<<dim3(49, 8, 16), dim3(256), 0, stream>>>(x, Xc);
  skconv_gemm<<<dim3(784), dim3(512), 0, stream>>>(Wc, Xc, zb, bias, out);
}

// Round 8
// 319.792 us; speedup vs baseline: 1.0526x; 1.0526x over previous
//
#include <hip/hip_runtime.h>
#include <hip/hip_bf16.h>

// SKConv2d == conv3x3(x, W_eff) + bias, W_eff = (sum_t S1@U1 + U2^T@S2)/12.
// Implicit GEMM, bf16 hi/lo Ootomo split, 3 MFMA passes (hh + hl + lh).
// Round-3 proven layouts/addressing + dbuf counted-vmcnt pipeline + persistent grid.

#define WC_ELEMS  (9*256*512)        // Wc[s][o][c8][8 chunks swizzled]  (2.25 MB)
#define XC_ELEMS  (16*3136*512)      // Xc[pixel][c8][hi32|lo32]         (49 MB)
#define ZB_ELEMS  512                // zero page (1024 B)

#define BUFSZ 40960                  // per LDS buf: A 32KB + B 8KB

typedef __attribute__((ext_vector_type(4))) float f32x4;
typedef __attribute__((ext_vector_type(8))) short short8;

__device__ __forceinline__ void gld16(const void* g, void* l) {
  __builtin_amdgcn_global_load_lds(
      (const __attribute__((address_space(1))) void*)g,
      (__attribute__((address_space(3))) void*)l, 16, 0, 0);
}

// ---------------------------------------------------------------------------
// Kernel 1: W_eff tiled: 144 blocks x 16 k-rows. Stages the [480 x 16] slice
// of {S1s, U2s^T} in LDS once; U1s/S2s rows read coalesced (o = tid).
// ---------------------------------------------------------------------------
__global__ __launch_bounds__(256) void build_w(
    const float* __restrict__ S1s, const float* __restrict__ S2s,
    const float* __restrict__ U1s, const float* __restrict__ U2s,
    unsigned short* __restrict__ Wc, float* __restrict__ zf)
{
  __shared__ __align__(16) float tile[480][16];   // 30 KB
  const int tid = threadIdx.x;
  const int k0 = blockIdx.x * 16;
  // S1: tile[t*8+r][kk] = S1s[t][k0+kk][r]
  for (int q = tid; q < 192; q += 256) {
    int tt = q >> 5, rem = q & 31, kk = rem >> 1, rh = rem & 1;
    float4 v = *(const float4*)&S1s[tt*18432 + (k0+kk)*8 + rh*4];
    tile[tt*8+rh*4+0][kk] = v.x; tile[tt*8+rh*4+1][kk] = v.y;
    tile[tt*8+rh*4+2][kk] = v.z; tile[tt*8+rh*4+3][kk] = v.w;
  }
  // U2: tile[48+i2][kk] = U2s[i2][k0+kk]  (row-contiguous float4)
  for (int q = tid; q < 1728; q += 256) {
    int i2 = q >> 2, part = q & 3;
    float4 v = *(const float4*)&U2s[(size_t)i2*2304 + k0 + part*4];
    *(float4*)&tile[48+i2][part*4] = v;
  }
  __syncthreads();
  const int o = tid;
  float acc[16];
  #pragma unroll
  for (int kk = 0; kk < 16; ++kk) acc[kk] = 0.f;
  #pragma unroll 4
  for (int i = 0; i < 48; ++i) {
    float rv = U1s[i*256 + o];
    #pragma unroll
    for (int kk = 0; kk < 16; ++kk) acc[kk] += tile[i][kk] * rv;
  }
  #pragma unroll 4
  for (int i = 0; i < 432; ++i) {
    float rv = S2s[i*256 + o];
    #pragma unroll
    for (int kk = 0; kk < 16; ++kk) acc[kk] += tile[48+i][kk] * rv;
  }
  #pragma unroll
  for (int kk = 0; kk < 16; ++kk) {
    float a = acc[kk] * (1.0f/12.0f);
    __hip_bfloat16 h = __float2bfloat16(a);
    float hv = __bfloat162float(h);
    __hip_bfloat16 l = __float2bfloat16(a - hv);
    int k = k0 + kk;
    int c = k / 9, s = k % 9;
    int base = s*131072 + o*512 + (c >> 5)*64 + (c & 31);
    Wc[base]      = *(const unsigned short*)&h;   // hi: chunk (c&31)>>3
    Wc[base + 32] = *(const unsigned short*)&l;   // lo: chunk +4
  }
  if (blockIdx.x == 0) zf[tid] = 0.f;             // 1 KB zero page
}

// ---------------------------------------------------------------------------
// Kernel 2: x [B][C][H][W] fp32 -> Xc [pixel][c8][hi32|lo32] bf16 hi/lo
// ---------------------------------------------------------------------------
__global__ __launch_bounds__(256) void split_x(
    const float* __restrict__ x, unsigned short* __restrict__ Xc)
{
  const int t  = threadIdx.x;
  const int sp = blockIdx.x*64 + (t >> 2);
  const int cg = blockIdx.y;           // 0..7
  const int b  = blockIdx.z;
  const int c0 = cg*32 + (t & 3)*8;
  const float* src = x + ((size_t)(b*256 + c0))*3136 + sp;
  __align__(16) unsigned short h8[8];
  __align__(16) unsigned short l8[8];
  #pragma unroll
  for (int j = 0; j < 8; ++j) {
    float v = src[(size_t)j*3136];
    __hip_bfloat16 h = __float2bfloat16(v);
    float hv = __bfloat162float(h);
    __hip_bfloat16 l = __float2bfloat16(v - hv);
    h8[j] = *(const unsigned short*)&h;
    l8[j] = *(const unsigned short*)&l;
  }
  unsigned short* dst = Xc + ((size_t)(b*3136 + sp))*512 + cg*64 + (t & 3)*8;
  *(uint4*)dst        = *(const uint4*)h8;
  *(uint4*)(dst + 32) = *(const uint4*)l8;
}

// ---------------------------------------------------------------------------
// Kernel 3: implicit-GEMM conv. BM=256(o) x BN=64(px) x BK=32, 8 waves (4o x 2n),
// 24 MFMA/step (hh+hl+lh), 72 steps/tile. Dbuf LDS 2x40KB; STAGE(t+1) in
// flight across COMPUTE(t) via counted vmcnt(5) (5 gld16/wave/stage, uniform).
// Persistent: 512 blocks (2/CU), 784 tiles -> exactly 3 tiles-worth per CU.
// A rows: [o][8x16B chunks], phys = logical ^ (o&7); B rows: [px][8 chunks]
// same swizzle (round-3 measured: 0 bank conflicts).
// ---------------------------------------------------------------------------
__global__ __launch_bounds__(512, 4) void skconv_gemm(
    const unsigned short* __restrict__ Wc, const unsigned short* __restrict__ Xc,
    const unsigned short* __restrict__ zb, const float* __restrict__ bias,
    float* __restrict__ out)
{
  extern __shared__ __align__(16) char lds[];    // 2 x BUFSZ
  const int t = threadIdx.x, lane = t & 63, wid = t >> 6;

  // A staging: 4 chunks/thread; 8 lanes cover one o-row's 128B (swizzled)
  int aoff0, aoff1, aoff2, aoff3;
  {
    int c, o, ph;
    c = 0*512 + t; o = c >> 3; ph = c & 7; aoff0 = o*512 + ((ph ^ (o & 7))*8);
    c = 1*512 + t; o = c >> 3; ph = c & 7; aoff1 = o*512 + ((ph ^ (o & 7))*8);
    c = 2*512 + t; o = c >> 3; ph = c & 7; aoff2 = o*512 + ((ph ^ (o & 7))*8);
    c = 3*512 + t; o = c >> 3; ph = c & 7; aoff3 = o*512 + ((ph ^ (o & 7))*8);
  }
  // B staging: 1 chunk/thread; 8 lanes per px row
  const int bn  = t >> 3;                        // px row 0..63
  const int bco = ((t & 7) ^ (bn & 7)) * 8;      // logical chunk ushort offset
  // fragment read offsets (bytes within buf)
  const int r15 = lane & 15, kc = lane >> 4;
  const int hsb = (kc ^ (lane & 7)) * 16;        // swizzled hi-chunk byte offset
  const int wr = wid >> 1, wcn = wid & 1;
  const int ard0 = (wr*64 +  0 + r15)*128 + hsb;
  const int ard1 = (wr*64 + 16 + r15)*128 + hsb;
  const int ard2 = (wr*64 + 32 + r15)*128 + hsb;
  const int ard3 = (wr*64 + 48 + r15)*128 + hsb;
  const int brd0 = 32768 + (wcn*32 +  0 + r15)*128 + hsb;
  const int brd1 = 32768 + (wcn*32 + 16 + r15)*128 + hsb;

  int bb, sp0v, prow, pcol;                      // per-tile (captured by ref)

  auto STAGE = [&](int bufb, int step) {
    const int s = step >> 3, c8 = step & 7;
    const unsigned short* as = Wc + s*131072 + c8*64;
    char* base = lds + bufb + wid*1024;          // wave-uniform LDS dests
    gld16(as + aoff0, base);
    gld16(as + aoff1, base + 8192);
    gld16(as + aoff2, base + 16384);
    gld16(as + aoff3, base + 24576);
    const int kh = s/3 - 1, kw = s%3 - 1;
    const int h2 = prow + kh, w2 = pcol + kw;
    const bool valid = ((unsigned)h2 < 56u) & ((unsigned)w2 < 56u);
    const unsigned short* bsrc = valid
        ? Xc + ((size_t)(bb*3136 + h2*56 + w2))*512 + c8*64 + bco
        : zb + c8*64 + bco;
    gld16(bsrc, base + 32768);
  };

  const f32x4 z4 = {0.f, 0.f, 0.f, 0.f};
  f32x4 acc[4][2];

  auto COMPUTE = [&](int bufb) {
    const char* L = lds + bufb;
    short8 bh0 = *(const short8*)(L + brd0);
    short8 bh1 = *(const short8*)(L + brd1);
    short8 bl0 = *(const short8*)(L + (brd0 ^ 64));
    short8 bl1 = *(const short8*)(L + (brd1 ^ 64));
    short8 ah0 = *(const short8*)(L + ard0);
    short8 ah1 = *(const short8*)(L + ard1);
    short8 ah2 = *(const short8*)(L + ard2);
    short8 ah3 = *(const short8*)(L + ard3);
    short8 al0 = *(const short8*)(L + (ard0 ^ 64));
    short8 al1 = *(const short8*)(L + (ard1 ^ 64));
    short8 al2 = *(const short8*)(L + (ard2 ^ 64));
    short8 al3 = *(const short8*)(L + (ard3 ^ 64));
    asm volatile("s_waitcnt lgkmcnt(0)" ::: "memory");
    __builtin_amdgcn_sched_barrier(0);
    __builtin_amdgcn_s_setprio(1);
    acc[0][0] = __builtin_amdgcn_mfma_f32_16x16x32_bf16(ah0, bh0, acc[0][0], 0,0,0);
    acc[0][1] = __builtin_amdgcn_mfma_f32_16x16x32_bf16(ah0, bh1, acc[0][1], 0,0,0);
    acc[1][0] = __builtin_amdgcn_mfma_f32_16x16x32_bf16(ah1, bh0, acc[1][0], 0,0,0);
    acc[1][1] = __builtin_amdgcn_mfma_f32_16x16x32_bf16(ah1, bh1, acc[1][1], 0,0,0);
    acc[2][0] = __builtin_amdgcn_mfma_f32_16x16x32_bf16(ah2, bh0, acc[2][0], 0,0,0);
    acc[2][1] = __builtin_amdgcn_mfma_f32_16x16x32_bf16(ah2, bh1, acc[2][1], 0,0,0);
    acc[3][0] = __builtin_amdgcn_mfma_f32_16x16x32_bf16(ah3, bh0, acc[3][0], 0,0,0);
    acc[3][1] = __builtin_amdgcn_mfma_f32_16x16x32_bf16(ah3, bh1, acc[3][1], 0,0,0);
    acc[0][0] = __builtin_amdgcn_mfma_f32_16x16x32_bf16(ah0, bl0, acc[0][0], 0,0,0);
    acc[0][1] = __builtin_amdgcn_mfma_f32_16x16x32_bf16(ah0, bl1, acc[0][1], 0,0,0);
    acc[1][0] = __builtin_amdgcn_mfma_f32_16x16x32_bf16(ah1, bl0, acc[1][0], 0,0,0);
    acc[1][1] = __builtin_amdgcn_mfma_f32_16x16x32_bf16(ah1, bl1, acc[1][1], 0,0,0);
    acc[2][0] = __builtin_amdgcn_mfma_f32_16x16x32_bf16(ah2, bl0, acc[2][0], 0,0,0);
    acc[2][1] = __builtin_amdgcn_mfma_f32_16x16x32_bf16(ah2, bl1, acc[2][1], 0,0,0);
    acc[3][0] = __builtin_amdgcn_mfma_f32_16x16x32_bf16(ah3, bl0, acc[3][0], 0,0,0);
    acc[3][1] = __builtin_amdgcn_mfma_f32_16x16x32_bf16(ah3, bl1, acc[3][1], 0,0,0);
    acc[0][0] = __builtin_amdgcn_mfma_f32_16x16x32_bf16(al0, bh0, acc[0][0], 0,0,0);
    acc[0][1] = __builtin_amdgcn_mfma_f32_16x16x32_bf16(al0, bh1, acc[0][1], 0,0,0);
    acc[1][0] = __builtin_amdgcn_mfma_f32_16x16x32_bf16(al1, bh0, acc[1][0], 0,0,0);
    acc[1][1] = __builtin_amdgcn_mfma_f32_16x16x32_bf16(al1, bh1, acc[1][1], 0,0,0);
    acc[2][0] = __builtin_amdgcn_mfma_f32_16x16x32_bf16(al2, bh0, acc[2][0], 0,0,0);
    acc[2][1] = __builtin_amdgcn_mfma_f32_16x16x32_bf16(al2, bh1, acc[2][1], 0,0,0);
    acc[3][0] = __builtin_amdgcn_mfma_f32_16x16x32_bf16(al3, bh0, acc[3][0], 0,0,0);
    acc[3][1] = __builtin_amdgcn_mfma_f32_16x16x32_bf16(al3, bh1, acc[3][1], 0,0,0);
    __builtin_amdgcn_s_setprio(0);
  };

  #pragma unroll 1
  for (int tv = blockIdx.x; tv < 784; tv += 512) {
    const int tile = (tv & 7)*98 + (tv >> 3);    // XCD-chunked (784 = 8*98)
    bb = tile / 49; sp0v = (tile % 49) * 64;
    const int p = sp0v + bn; prow = p / 56; pcol = p % 56;
    #pragma unroll
    for (int mi = 0; mi < 4; ++mi) { acc[mi][0] = z4; acc[mi][1] = z4; }

    STAGE(0, 0);
    #pragma unroll 1
    for (int step = 0; step < 72; step += 2) {
      STAGE(BUFSZ, step + 1);
      asm volatile("s_waitcnt vmcnt(5)" ::: "memory");  // buf0 stage retired
      __builtin_amdgcn_s_barrier();
      COMPUTE(0);
      __builtin_amdgcn_s_barrier();                     // buf0 reads complete
      if (step + 2 < 72) {
        STAGE(0, step + 2);
        asm volatile("s_waitcnt vmcnt(5)" ::: "memory");
      } else {
        asm volatile("s_waitcnt vmcnt(0)" ::: "memory");
      }
      __builtin_amdgcn_s_barrier();
      COMPUTE(BUFSZ);
      __builtin_amdgcn_s_barrier();
    }

    // epilogue: D col=lane&15 -> px (contiguous 64B stores), rows -> o
    const int nbase = sp0v + wcn*32 + r15;
    #pragma unroll
    for (int mi = 0; mi < 4; ++mi) {
      const int o0 = wr*64 + mi*16 + kc*4;
      float4 bv = *(const float4*)&bias[o0];
      const float bvr[4] = {bv.x, bv.y, bv.z, bv.w};
      #pragma unroll
      for (int ni = 0; ni < 2; ++ni) {
        #pragma unroll
        for (int r = 0; r < 4; ++r) {
          out[((size_t)(bb*256 + o0 + r))*3136 + nbase + ni*16]
              = acc[mi][ni][r] + bvr[r];
        }
      }
    }
  }
}

extern "C" void kernel_launch(void* const* d_in, const int* in_sizes, int n_in,
                              void* d_out, int out_size, void* d_ws, size_t ws_size,
                              hipStream_t stream) {
  const float* x    = (const float*)d_in[0];
  const float* S1s  = (const float*)d_in[1];
  const float* S2s  = (const float*)d_in[2];
  const float* U1s  = (const float*)d_in[3];
  const float* U2s  = (const float*)d_in[4];
  const float* bias = (const float*)d_in[5];
  float* out = (float*)d_out;

  unsigned short* Wc = (unsigned short*)d_ws;
  unsigned short* Xc = Wc + WC_ELEMS;
  unsigned short* zbuf = Xc + XC_ELEMS;
  // ws required ~53.7 MB; every region rewritten each call (re-poison safe).

  // 80 KB dynamic LDS opt-in (host-side attribute, not a stream op)
  (void)hipFuncSetAttribute(reinterpret_cast<const void*>(skconv_gemm),
                            hipFuncAttributeMaxDynamicSharedMemorySize, 2*BUFSZ);

  build_w<<<dim3(144), dim3(256), 0, stream>>>(S1s, S2s, U1s, U2s, Wc, (float*)zbuf);
  split_x<<<dim3(49, 8, 16), dim3(256), 0, stream>>>(x, Xc);
  skconv_gemm<<<dim3(512), dim3(512), 2*BUFSZ, stream>>>(Wc, Xc, zbuf, bias, out);
}